// Round 3
// baseline (13002.342 us; speedup 1.0000x reference)
//
#include <hip/hip_runtime.h>
#include <math.h>

#define NTHR 1024

constexpr int CMAX = 16;                      // max rows per MLP chunk
constexpr int E_TOTAL   = 32640;              // (128+64+...+1)*128
constexpr int WS_STRIDE = E_TOTAL;            // floats per batch

__device__ __forceinline__ int eoff(int l) { return (256 - (512 >> l)) * 128; } // l in 1..8
__device__ __forceinline__ int xoff(int l) { return 512 - (512 >> l); }         // l in 0..7

// ---------------- one MLP chunk: out = relu(z@W1+b1 [+lab1[u1h]])@W2+b2 ----
// z: C x 256 (LDS), h: C x 256 (LDS), red: CMAX*1024 floats (LDS),
// eout: C x 128 (global e-buffer). KIN is always 256 (bit-stage E_lab term is
// folded into the per-row bias `lab`).
// Layer1: 1024 thr = 256 hidden cols x 4 K-slices of 64; LDS reduce.
// Layer2: 1024 thr = 128 out cols x 8 K-slices of 32; LDS reduce.
// Every weight element is read exactly once per chunk per block.
template <int C>
__device__ void mlp_chunk(const float* __restrict__ z,
                          const float* __restrict__ W1, const float* __restrict__ B1,
                          const float* __restrict__ W2, const float* __restrict__ B2,
                          const float* __restrict__ lab,   // LDS 2x256, or nullptr
                          const int*   __restrict__ u1h,   // LDS bits, or nullptr
                          int done,
                          float* __restrict__ h, float* __restrict__ red,
                          float* __restrict__ eout)
{
  const int t = threadIdx.x;
  // ---------------- layer 1 ----------------
  {
    const int hcol = t & 255;
    const int s    = t >> 8;          // K-slice 0..3
    const int k0   = s * 64;
    const float* Wp = W1 + hcol;
    float acc[C];
#pragma unroll
    for (int r = 0; r < C; ++r) acc[r] = 0.0f;
    for (int kk = k0; kk < k0 + 64; kk += 4) {
      const float w0 = Wp[(kk + 0) * 256];
      const float w1 = Wp[(kk + 1) * 256];
      const float w2 = Wp[(kk + 2) * 256];
      const float w3 = Wp[(kk + 3) * 256];
#pragma unroll
      for (int r = 0; r < C; ++r) {
        const float4 z4 = *reinterpret_cast<const float4*>(z + r * 256 + kk);
        acc[r] = fmaf(z4.x, w0, acc[r]);
        acc[r] = fmaf(z4.y, w1, acc[r]);
        acc[r] = fmaf(z4.z, w2, acc[r]);
        acc[r] = fmaf(z4.w, w3, acc[r]);
      }
    }
#pragma unroll
    for (int r = 0; r < C; ++r) red[(s * C + r) * 256 + hcol] = acc[r];
    __syncthreads();
    for (int idx = t; idx < 256 * C; idx += NTHR) {
      const int h2 = idx & 255, r2 = idx >> 8;
      float sum = red[(0 * C + r2) * 256 + h2] + red[(1 * C + r2) * 256 + h2]
                + red[(2 * C + r2) * 256 + h2] + red[(3 * C + r2) * 256 + h2];
      sum += B1[h2];
      if (lab) sum += lab[u1h[done + r2] * 256 + h2];
      h[r2 * 256 + h2] = sum > 0.0f ? sum : 0.0f;
    }
    __syncthreads();
  }
  // ---------------- layer 2 ----------------
  {
    const int d  = t & 127;
    const int q  = t >> 7;            // K-slice 0..7
    const int k0 = q * 32;
    const float* Wp = W2 + d;
    float acc[C];
#pragma unroll
    for (int r = 0; r < C; ++r) acc[r] = 0.0f;
    for (int k = k0; k < k0 + 32; k += 4) {
      const float w0 = Wp[(k + 0) * 128];
      const float w1 = Wp[(k + 1) * 128];
      const float w2 = Wp[(k + 2) * 128];
      const float w3 = Wp[(k + 3) * 128];
#pragma unroll
      for (int r = 0; r < C; ++r) {
        const float4 h4 = *reinterpret_cast<const float4*>(h + r * 256 + k);
        acc[r] = fmaf(h4.x, w0, acc[r]);
        acc[r] = fmaf(h4.y, w1, acc[r]);
        acc[r] = fmaf(h4.z, w2, acc[r]);
        acc[r] = fmaf(h4.w, w3, acc[r]);
      }
    }
#pragma unroll
    for (int r = 0; r < C; ++r) red[(q * C + r) * 128 + d] = acc[r];
    __syncthreads();
    for (int idx = t; idx < 128 * C; idx += NTHR) {
      const int d2 = idx & 127, r2 = idx >> 7;
      float sum = B2[d2];
#pragma unroll
      for (int q2 = 0; q2 < 8; ++q2) sum += red[(q2 * C + r2) * 128 + d2];
      eout[r2 * 128 + d2] = sum;
    }
    __syncthreads();
  }
}

// ---------------- one stage; KIN folded to 256 for both stage types --------
__device__ void run_stage(const float* ein, int rows, const int* u1h,
                          const float* __restrict__ W1, const float* __restrict__ B1,
                          const float* __restrict__ W2, const float* __restrict__ B2,
                          const float* __restrict__ eobs2, const float* __restrict__ lab,
                          float* __restrict__ z_lds, float* __restrict__ h_lds,
                          float* __restrict__ red_lds,
                          float* __restrict__ eout)
{
  const int t = threadIdx.x;
  int done = 0;
  while (done < rows) {
    int c = rows - done;
    if (c > CMAX) c = CMAX;
    // z chunk = rows [done, done+c) of ein, i.e. a straight contiguous copy
    // (row r of z = e[2r] | e[2r+1] which are adjacent in the level buffer).
    const int total = c * 256;
    if (ein) {
      const float* src = ein + done * 256;
      for (int idx = 4 * t; idx < total; idx += 4 * NTHR)
        *reinterpret_cast<float4*>(z_lds + idx) =
            *reinterpret_cast<const float4*>(src + idx);
    } else {
      for (int idx = t; idx < total; idx += NTHR)
        z_lds[idx] = eobs2[idx & 127];
    }
    __syncthreads();
    float* eo = eout + done * 128;
    switch (c) {
      case 16: mlp_chunk<16>(z_lds, W1, B1, W2, B2, lab, u1h, done, h_lds, red_lds, eo); break;
      case 8:  mlp_chunk<8 >(z_lds, W1, B1, W2, B2, lab, u1h, done, h_lds, red_lds, eo); break;
      case 4:  mlp_chunk<4 >(z_lds, W1, B1, W2, B2, lab, u1h, done, h_lds, red_lds, eo); break;
      case 2:  mlp_chunk<2 >(z_lds, W1, B1, W2, B2, lab, u1h, done, h_lds, red_lds, eo); break;
      default: mlp_chunk<1 >(z_lds, W1, B1, W2, B2, lab, u1h, done, h_lds, red_lds, eo); break;
    }
    done += c;
  }
}

__global__ void sc_setup(const int* __restrict__ info_set,
                         const float* __restrict__ E_lab,
                         const float* __restrict__ Wb1,
                         int* __restrict__ pos2k, float* __restrict__ lab1)
{
  const int t = threadIdx.x;   // 256 threads
  pos2k[t] = -1;
  __syncthreads();
  if (t < 128) pos2k[info_set[t]] = t;
  // lab1[j][h] = sum_k E_lab[j,k] * Wb1[256+k, h]
  for (int j = 0; j < 2; ++j) {
    float s = 0.0f;
    for (int k = 0; k < 128; ++k)
      s = fmaf(E_lab[j * 128 + k], Wb1[(256 + k) * 256 + t], s);
    lab1[j * 256 + t] = s;
  }
}

__global__ __launch_bounds__(NTHR, 1)
void sc_main(const int* __restrict__ info_bits, const float* __restrict__ rin,
             const float* __restrict__ E_obs, const float* __restrict__ E_lab,
             const float* __restrict__ Wc1, const float* __restrict__ bc1,
             const float* __restrict__ Wc2, const float* __restrict__ bc2,
             const float* __restrict__ Wb1, const float* __restrict__ bb1,
             const float* __restrict__ Wb2, const float* __restrict__ bb2,
             const float* __restrict__ Wl, const float* __restrict__ bl,
             const int* __restrict__ pos2k, const float* __restrict__ lab1_g,
             float* __restrict__ wsall, float* __restrict__ out)
{
  const int b = blockIdx.x;   // one block per batch element
  const int t = threadIdx.x;
  float* bws = wsall + (size_t)b * WS_STRIDE;
  const float* eobs2 = E_obs + 2 * 128;

  __shared__ float z_lds[CMAX * 256];     // 16 KB
  __shared__ float h_lds[CMAX * 256];     // 16 KB
  __shared__ float red_lds[CMAX * 1024];  // 64 KB
  __shared__ float lab_lds[512];          //  2 KB
  __shared__ int   xh[512];               //  2 KB

  for (int idx = t; idx < 512; idx += NTHR) lab_lds[idx] = lab1_g[idx];
  __syncthreads();

  float* xO = out;
  float* fO = out + 32768;
  float* uO = out + 65536;
  float* pO = out + 98304;
  float* rO = out + 131072;

  auto ebuf = [&](int l) -> float* { return bws + eoff(l); };

  auto do_check = [&](int l) {
    const float* ein = (l == 0) ? nullptr : ebuf(l);
    run_stage(ein, 128 >> l, nullptr, Wc1, bc1, Wc2, bc2, eobs2, nullptr,
              z_lds, h_lds, red_lds, ebuf(l + 1));
  };
  auto do_bit = [&](int l) {
    const float* ein = (l == 0) ? nullptr : ebuf(l);
    run_stage(ein, 128 >> l, xh + xoff(l), Wb1, bb1, Wb2, bb2, eobs2, lab_lds,
              z_lds, h_lds, red_lds, ebuf(l + 1));
  };
  auto do_leaf = [&](int i) {
    const float* e = ebuf(8);  // 1 row, 128 floats
    if (t < 64) {
      float partial = e[t] * Wl[t] + e[t + 64] * Wl[t + 64];
#pragma unroll
      for (int m = 32; m >= 1; m >>= 1) partial += __shfl_xor(partial, m);
      if (t == 0) {
        const float tv = partial + bl[0];
        const float p  = 1.0f / (1.0f + expf(-tv));
        const float rv = rin[b * 256 + i];
        const int  hd     = (rv > p) ? 1 : 0;
        const bool frozen = fabsf(p - 0.5f) > 0.25f;
        const int  k  = pos2k[i];
        const int  fc = (k >= 0) ? info_bits[b * 128 + k] : 2;
        const int  x  = (fc == 2 || frozen) ? hd : fc;
        xh[xoff(7) + (i & 1)] = x;
        pO[b * 256 + i] = p;
        uO[b * 256 + i] = (float)x;
        fO[b * 256 + i] = (k >= 0) ? 2.0f : 1.0f;
        rO[b * 256 + i] = rv;
      }
    }
    __syncthreads();
  };
  auto do_combine = [&](int l, int side) {
    const int n = 256 >> l, half = n >> 1;
    if (t < half) {
      const int u1 = xh[xoff(l) + t];
      const int u2 = xh[xoff(l) + half + t];
      if (l > 0) {
        const int base = xoff(l - 1) + side * n;
        xh[base + 2 * t]     = u1 ^ u2;
        xh[base + 2 * t + 1] = u2;
      } else {
        xO[b * 256 + 2 * t]     = (float)(u1 ^ u2);
        xO[b * 256 + 2 * t + 1] = (float)u2;
      }
    }
    __syncthreads();
  };

  // initial descent to leaf 0
  for (int l = 0; l < 8; ++l) do_check(l);
  do_leaf(0);

  for (int i = 1; i < 256; ++i) {
    const int s = __builtin_ctz(i);
    // fold completed subtrees upward; last fold lands as u1h (side 0)
    for (int j = 1; j <= s; ++j) do_combine(8 - j, (j < s) ? 1 : 0);
    const int lb = 7 - s;
    do_bit(lb);
    for (int l = lb + 1; l < 8; ++l) do_check(l);
    do_leaf(i);
  }
  // final folds; level-0 combine writes the codeword x
  for (int j = 1; j <= 8; ++j) do_combine(8 - j, 1);
}

extern "C" void kernel_launch(void* const* d_in, const int* in_sizes, int n_in,
                              void* d_out, int out_size, void* d_ws, size_t ws_size,
                              hipStream_t stream)
{
  const int*   info_bits = (const int*)  d_in[0];
  const float* rin       = (const float*)d_in[1];
  const int*   info_set  = (const int*)  d_in[2];
  const float* E_obs     = (const float*)d_in[3];
  const float* E_lab     = (const float*)d_in[4];
  const float* Wc1 = (const float*)d_in[5];
  const float* bc1 = (const float*)d_in[6];
  const float* Wc2 = (const float*)d_in[7];
  const float* bc2 = (const float*)d_in[8];
  const float* Wb1 = (const float*)d_in[9];
  const float* bb1 = (const float*)d_in[10];
  const float* Wb2 = (const float*)d_in[11];
  const float* bb2 = (const float*)d_in[12];
  const float* Wl  = (const float*)d_in[13];
  const float* bl  = (const float*)d_in[14];

  int*   pos2k = (int*)d_ws;                 // 256 ints
  float* lab1  = (float*)d_ws + 256;         // 512 floats
  float* wsall = (float*)d_ws + 768;

  hipLaunchKernelGGL(sc_setup, dim3(1), dim3(256), 0, stream,
                     info_set, E_lab, Wb1, pos2k, lab1);
  hipLaunchKernelGGL(sc_main, dim3(128), dim3(NTHR), 0, stream,
                     info_bits, rin, E_obs, E_lab,
                     Wc1, bc1, Wc2, bc2, Wb1, bb1, Wb2, bb2, Wl, bl,
                     pos2k, lab1, wsall, (float*)d_out);
}

// Round 4
// 8661.415 us; speedup vs baseline: 1.5012x; 1.5012x over previous
//
#include <hip/hip_runtime.h>
#include <math.h>

#define NTHR 1024

constexpr int CMAX = 8;                       // rows per MLP chunk
constexpr int E_TOTAL   = 32640;              // (128+64+...+1)*128
constexpr int WS_STRIDE = E_TOTAL;            // floats per batch

__device__ __forceinline__ int eoff(int l) { return (256 - (512 >> l)) * 128; } // l in 1..8
__device__ __forceinline__ int xoff(int l) { return 512 - (512 >> l); }         // l in 0..7

// ---------------- one MLP chunk: out = relu(z@W1+b1 [+lab1[u1h]])@W2+b2 ----
// z read straight from GLOBAL (wave-uniform float4 broadcast, L1-hot).
// zstride = 256 normally, 0 for the uniform root row.
// h: C x 256 (LDS). red: 8192 floats (32 KB LDS) for split-K partials.
// Layer1: 1024 thr = 256 cols x 4 K-slices of 64. acc[C<=8]. 1x weight reads.
// Layer2: 1024 thr = 128 cols x 8 K-slices of 32. acc[C<=8]. 1x weight reads.
template <int C>
__device__ void mlp_chunk(const float* __restrict__ zbase, int zstride,
                          const float* __restrict__ W1, const float* __restrict__ B1,
                          const float* __restrict__ W2, const float* __restrict__ B2,
                          const float* __restrict__ lab,   // LDS 2x256, or nullptr
                          const int*   __restrict__ u1h,   // LDS bits, or nullptr
                          int done,
                          float* __restrict__ h, float* __restrict__ red,
                          float* __restrict__ eout)
{
  const int t = threadIdx.x;
  // ---------------- layer 1 ----------------
  {
    const int col = t & 255;
    const int s   = t >> 8;          // K-slice 0..3, 64 k each
    const int k0  = s * 64;
    const float* Wp = W1 + col;
    float acc[C];
#pragma unroll
    for (int r = 0; r < C; ++r) acc[r] = 0.0f;
#pragma unroll 4
    for (int q = 0; q < 16; ++q) {
      const int kk = k0 + 4 * q;
      const float w0 = Wp[(kk + 0) * 256];
      const float w1 = Wp[(kk + 1) * 256];
      const float w2 = Wp[(kk + 2) * 256];
      const float w3 = Wp[(kk + 3) * 256];
#pragma unroll
      for (int r = 0; r < C; ++r) {
        const float4 z4 = *reinterpret_cast<const float4*>(zbase + r * zstride + kk);
        acc[r] = fmaf(z4.x, w0, acc[r]);
        acc[r] = fmaf(z4.y, w1, acc[r]);
        acc[r] = fmaf(z4.z, w2, acc[r]);
        acc[r] = fmaf(z4.w, w3, acc[r]);
      }
    }
#pragma unroll
    for (int r = 0; r < C; ++r) red[(s * C + r) * 256 + col] = acc[r];
  }
  __syncthreads();
  // layer-1 reduce: 4 partials + bias (+ folded E_lab term), relu -> h (LDS)
  for (int idx = t; idx < 256 * C; idx += NTHR) {
    const int c2 = idx & 255, r2 = idx >> 8;
    float sum = red[(0 * C + r2) * 256 + c2] + red[(1 * C + r2) * 256 + c2]
              + red[(2 * C + r2) * 256 + c2] + red[(3 * C + r2) * 256 + c2];
    sum += B1[c2];
    if (lab) sum += lab[u1h[done + r2] * 256 + c2];
    h[r2 * 256 + c2] = sum > 0.0f ? sum : 0.0f;
  }
  __syncthreads();
  // ---------------- layer 2 ----------------
  {
    const int d  = t & 127;
    const int q  = t >> 7;           // K-slice 0..7, 32 k each
    const int k0 = q * 32;
    const float* Wp = W2 + d;
    float acc[C];
#pragma unroll
    for (int r = 0; r < C; ++r) acc[r] = 0.0f;
#pragma unroll 2
    for (int qq = 0; qq < 8; ++qq) {
      const int kk = k0 + 4 * qq;
      const float w0 = Wp[(kk + 0) * 128];
      const float w1 = Wp[(kk + 1) * 128];
      const float w2 = Wp[(kk + 2) * 128];
      const float w3 = Wp[(kk + 3) * 128];
#pragma unroll
      for (int r = 0; r < C; ++r) {
        const float4 h4 = *reinterpret_cast<const float4*>(h + r * 256 + kk);
        acc[r] = fmaf(h4.x, w0, acc[r]);
        acc[r] = fmaf(h4.y, w1, acc[r]);
        acc[r] = fmaf(h4.z, w2, acc[r]);
        acc[r] = fmaf(h4.w, w3, acc[r]);
      }
    }
#pragma unroll
    for (int r = 0; r < C; ++r) red[(q * C + r) * 128 + d] = acc[r];
  }
  __syncthreads();
  // layer-2 reduce: 8 partials + bias -> eout (global)
  for (int idx = t; idx < 128 * C; idx += NTHR) {
    const int d2 = idx & 127, r2 = idx >> 7;
    float sum = B2[d2];
#pragma unroll
    for (int q2 = 0; q2 < 8; ++q2) sum += red[(q2 * C + r2) * 128 + d2];
    eout[r2 * 128 + d2] = sum;
  }
  __syncthreads();
}

// ---------------- one stage; KIN folded to 256 for both stage types --------
__device__ void run_stage(const float* ein, const float* eroot, int rows,
                          const int* u1h,
                          const float* __restrict__ W1, const float* __restrict__ B1,
                          const float* __restrict__ W2, const float* __restrict__ B2,
                          const float* __restrict__ lab,
                          float* __restrict__ h_lds, float* __restrict__ red_lds,
                          float* __restrict__ eout)
{
  int done = 0;
  while (done < rows) {
    int c = rows - done;
    if (c > CMAX) c = CMAX;
    const float* zb = ein ? ein + done * 256 : eroot;
    const int    zs = ein ? 256 : 0;
    float* eo = eout + done * 128;
    switch (c) {
      case 8:  mlp_chunk<8>(zb, zs, W1, B1, W2, B2, lab, u1h, done, h_lds, red_lds, eo); break;
      case 4:  mlp_chunk<4>(zb, zs, W1, B1, W2, B2, lab, u1h, done, h_lds, red_lds, eo); break;
      case 2:  mlp_chunk<2>(zb, zs, W1, B1, W2, B2, lab, u1h, done, h_lds, red_lds, eo); break;
      default: mlp_chunk<1>(zb, zs, W1, B1, W2, B2, lab, u1h, done, h_lds, red_lds, eo); break;
    }
    done += c;
  }
}

__global__ void sc_setup(const int* __restrict__ info_set,
                         const float* __restrict__ E_obs,
                         const float* __restrict__ E_lab,
                         const float* __restrict__ Wb1,
                         int* __restrict__ pos2k, float* __restrict__ lab1,
                         float* __restrict__ eroot)
{
  const int t = threadIdx.x;   // 256 threads
  pos2k[t] = -1;
  __syncthreads();
  if (t < 128) pos2k[info_set[t]] = t;
  eroot[t] = E_obs[2 * 128 + (t & 127)];
  // lab1[j][h] = sum_k E_lab[j,k] * Wb1[256+k, h]
  for (int j = 0; j < 2; ++j) {
    float s = 0.0f;
    for (int k = 0; k < 128; ++k)
      s = fmaf(E_lab[j * 128 + k], Wb1[(256 + k) * 256 + t], s);
    lab1[j * 256 + t] = s;
  }
}

__global__ __launch_bounds__(NTHR, 2)
void sc_main(const int* __restrict__ info_bits, const float* __restrict__ rin,
             const float* __restrict__ Wc1, const float* __restrict__ bc1,
             const float* __restrict__ Wc2, const float* __restrict__ bc2,
             const float* __restrict__ Wb1, const float* __restrict__ bb1,
             const float* __restrict__ Wb2, const float* __restrict__ bb2,
             const float* __restrict__ Wl, const float* __restrict__ bl,
             const int* __restrict__ pos2k, const float* __restrict__ lab1_g,
             const float* __restrict__ eroot,
             float* __restrict__ wsall, float* __restrict__ out)
{
  const int b = blockIdx.x;   // one block per batch element
  const int t = threadIdx.x;
  float* bws = wsall + (size_t)b * WS_STRIDE;

  __shared__ float h_lds[CMAX * 256];     //  8 KB
  __shared__ float red_lds[8192];         // 32 KB
  __shared__ float lab_lds[512];          //  2 KB
  __shared__ int   xh[512];               //  2 KB

  for (int idx = t; idx < 512; idx += NTHR) lab_lds[idx] = lab1_g[idx];
  __syncthreads();

  float* xO = out;
  float* fO = out + 32768;
  float* uO = out + 65536;
  float* pO = out + 98304;
  float* rO = out + 131072;

  auto ebuf = [&](int l) -> float* { return bws + eoff(l); };

  auto do_check = [&](int l) {
    const float* ein = (l == 0) ? nullptr : ebuf(l);
    run_stage(ein, eroot, 128 >> l, nullptr, Wc1, bc1, Wc2, bc2, nullptr,
              h_lds, red_lds, ebuf(l + 1));
  };
  auto do_bit = [&](int l) {
    const float* ein = (l == 0) ? nullptr : ebuf(l);
    run_stage(ein, eroot, 128 >> l, xh + xoff(l), Wb1, bb1, Wb2, bb2, lab_lds,
              h_lds, red_lds, ebuf(l + 1));
  };
  auto do_leaf = [&](int i) {
    const float* e = ebuf(8);  // 1 row, 128 floats
    if (t < 64) {
      float partial = e[t] * Wl[t] + e[t + 64] * Wl[t + 64];
#pragma unroll
      for (int m = 32; m >= 1; m >>= 1) partial += __shfl_xor(partial, m);
      if (t == 0) {
        const float tv = partial + bl[0];
        const float p  = 1.0f / (1.0f + expf(-tv));
        const float rv = rin[b * 256 + i];
        const int  hd     = (rv > p) ? 1 : 0;
        const bool frozen = fabsf(p - 0.5f) > 0.25f;
        const int  k  = pos2k[i];
        const int  fc = (k >= 0) ? info_bits[b * 128 + k] : 2;
        const int  x  = (fc == 2 || frozen) ? hd : fc;
        xh[xoff(7) + (i & 1)] = x;
        pO[b * 256 + i] = p;
        uO[b * 256 + i] = (float)x;
        fO[b * 256 + i] = (k >= 0) ? 2.0f : 1.0f;
        rO[b * 256 + i] = rv;
      }
    }
    __syncthreads();
  };
  auto do_combine = [&](int l, int side) {
    const int n = 256 >> l, half = n >> 1;
    if (t < half) {
      const int u1 = xh[xoff(l) + t];
      const int u2 = xh[xoff(l) + half + t];
      if (l > 0) {
        const int base = xoff(l - 1) + side * n;
        xh[base + 2 * t]     = u1 ^ u2;
        xh[base + 2 * t + 1] = u2;
      } else {
        xO[b * 256 + 2 * t]     = (float)(u1 ^ u2);
        xO[b * 256 + 2 * t + 1] = (float)u2;
      }
    }
    __syncthreads();
  };

  // initial descent to leaf 0
  for (int l = 0; l < 8; ++l) do_check(l);
  do_leaf(0);

  for (int i = 1; i < 256; ++i) {
    const int s = __builtin_ctz(i);
    // fold completed subtrees upward; last fold lands as u1h (side 0)
    for (int j = 1; j <= s; ++j) do_combine(8 - j, (j < s) ? 1 : 0);
    const int lb = 7 - s;
    do_bit(lb);
    for (int l = lb + 1; l < 8; ++l) do_check(l);
    do_leaf(i);
  }
  // final folds; level-0 combine writes the codeword x
  for (int j = 1; j <= 8; ++j) do_combine(8 - j, 1);
}

extern "C" void kernel_launch(void* const* d_in, const int* in_sizes, int n_in,
                              void* d_out, int out_size, void* d_ws, size_t ws_size,
                              hipStream_t stream)
{
  const int*   info_bits = (const int*)  d_in[0];
  const float* rin       = (const float*)d_in[1];
  const int*   info_set  = (const int*)  d_in[2];
  const float* E_obs     = (const float*)d_in[3];
  const float* E_lab     = (const float*)d_in[4];
  const float* Wc1 = (const float*)d_in[5];
  const float* bc1 = (const float*)d_in[6];
  const float* Wc2 = (const float*)d_in[7];
  const float* bc2 = (const float*)d_in[8];
  const float* Wb1 = (const float*)d_in[9];
  const float* bb1 = (const float*)d_in[10];
  const float* Wb2 = (const float*)d_in[11];
  const float* bb2 = (const float*)d_in[12];
  const float* Wl  = (const float*)d_in[13];
  const float* bl  = (const float*)d_in[14];

  int*   pos2k = (int*)d_ws;                 // 256 ints
  float* lab1  = (float*)d_ws + 256;         // 512 floats
  float* eroot = (float*)d_ws + 768;         // 256 floats
  float* wsall = (float*)d_ws + 1024;

  hipLaunchKernelGGL(sc_setup, dim3(1), dim3(256), 0, stream,
                     info_set, E_obs, E_lab, Wb1, pos2k, lab1, eroot);
  hipLaunchKernelGGL(sc_main, dim3(128), dim3(NTHR), 0, stream,
                     info_bits, rin,
                     Wc1, bc1, Wc2, bc2, Wb1, bb1, Wb2, bb2, Wl, bl,
                     pos2k, lab1, eroot, wsall, (float*)d_out);
}

// Round 5
// 8656.322 us; speedup vs baseline: 1.5021x; 1.0006x over previous
//
#include <hip/hip_runtime.h>
#include <math.h>

#define NTHR 1024

constexpr int CMAX = 8;                 // rows per MLP chunk
constexpr int L1_SIZE = 16384;          // level-1 e-buffer floats (global, per batch)

__device__ __forceinline__ int xoff(int l) { return 512 - (512 >> l); }   // l in 0..7
// LDS offsets for e levels 2..8 (floats)
__device__ __forceinline__ int ldse(int l) { return 16384 - (32768 >> (l - 1)); }

// ---------------- one MLP chunk: out = relu(z@W1+b1 [+lab1[u1h]])@W2+b2 ----
// z: C rows (LDS broadcast or global/root), zstride 256 or 0 (root).
// h: C x 256 (LDS). red: 8192-float LDS split-K partial buffer.
// Layer1: 1024 thr = 256 cols x 4 K-slices of 64; weights read once/chunk.
// Layer2: 1024 thr = 128 cols x 8 K-slices of 32; weights read once/chunk.
// Weight regs double-buffered one group ahead; q-loop not unrolled so the
// live set stays ~30 VGPRs (no scratch spill at the 64-VGPR budget).
template <int C>
__device__ void mlp_chunk(const float* __restrict__ z, int zstride,
                          const float* __restrict__ W1, const float* __restrict__ B1,
                          const float* __restrict__ W2, const float* __restrict__ B2,
                          const float* __restrict__ lab,   // LDS 2x256, or nullptr
                          const int*   __restrict__ u1h,   // LDS bits, or nullptr
                          int done,
                          float* __restrict__ h, float* __restrict__ red,
                          float* __restrict__ eout)
{
  const int t = threadIdx.x;
  // ---------------- layer 1 ----------------
  {
    const int col = t & 255;
    const int s   = t >> 8;          // K-slice 0..3, 64 k each
    const int k0  = s * 64;
    const float* Wp = W1 + col;
    float w0 = Wp[(k0 + 0) * 256];
    float w1 = Wp[(k0 + 1) * 256];
    float w2 = Wp[(k0 + 2) * 256];
    float w3 = Wp[(k0 + 3) * 256];
    float acc[C];
#pragma unroll
    for (int r = 0; r < C; ++r) acc[r] = 0.0f;
#pragma unroll 1
    for (int q = 0; q < 16; ++q) {
      const int kk = k0 + 4 * q;
      const int kn = (q < 15) ? kk + 4 : k0;     // branchless prefetch index
      const float n0 = Wp[(kn + 0) * 256];
      const float n1 = Wp[(kn + 1) * 256];
      const float n2 = Wp[(kn + 2) * 256];
      const float n3 = Wp[(kn + 3) * 256];
#pragma unroll
      for (int r = 0; r < C; ++r) {
        const float4 z4 = *reinterpret_cast<const float4*>(z + r * zstride + kk);
        acc[r] = fmaf(z4.x, w0, acc[r]);
        acc[r] = fmaf(z4.y, w1, acc[r]);
        acc[r] = fmaf(z4.z, w2, acc[r]);
        acc[r] = fmaf(z4.w, w3, acc[r]);
      }
      w0 = n0; w1 = n1; w2 = n2; w3 = n3;
    }
#pragma unroll
    for (int r = 0; r < C; ++r) red[(s * C + r) * 256 + col] = acc[r];
  }
  __syncthreads();
  // layer-1 reduce: 4 partials + bias (+ folded E_lab term), relu -> h (LDS)
  for (int idx = t; idx < 256 * C; idx += NTHR) {
    const int c2 = idx & 255, r2 = idx >> 8;
    float sum = red[(0 * C + r2) * 256 + c2] + red[(1 * C + r2) * 256 + c2]
              + red[(2 * C + r2) * 256 + c2] + red[(3 * C + r2) * 256 + c2];
    sum += B1[c2];
    if (lab) sum += lab[u1h[done + r2] * 256 + c2];
    h[r2 * 256 + c2] = sum > 0.0f ? sum : 0.0f;
  }
  __syncthreads();
  // ---------------- layer 2 ----------------
  {
    const int d  = t & 127;
    const int q  = t >> 7;           // K-slice 0..7, 32 k each
    const int k0 = q * 32;
    const float* Wp = W2 + d;
    float w0 = Wp[(k0 + 0) * 128];
    float w1 = Wp[(k0 + 1) * 128];
    float w2 = Wp[(k0 + 2) * 128];
    float w3 = Wp[(k0 + 3) * 128];
    float acc[C];
#pragma unroll
    for (int r = 0; r < C; ++r) acc[r] = 0.0f;
#pragma unroll 1
    for (int qq = 0; qq < 8; ++qq) {
      const int kk = k0 + 4 * qq;
      const int kn = (qq < 7) ? kk + 4 : k0;
      const float n0 = Wp[(kn + 0) * 128];
      const float n1 = Wp[(kn + 1) * 128];
      const float n2 = Wp[(kn + 2) * 128];
      const float n3 = Wp[(kn + 3) * 128];
#pragma unroll
      for (int r = 0; r < C; ++r) {
        const float4 h4 = *reinterpret_cast<const float4*>(h + r * 256 + kk);
        acc[r] = fmaf(h4.x, w0, acc[r]);
        acc[r] = fmaf(h4.y, w1, acc[r]);
        acc[r] = fmaf(h4.z, w2, acc[r]);
        acc[r] = fmaf(h4.w, w3, acc[r]);
      }
      w0 = n0; w1 = n1; w2 = n2; w3 = n3;
    }
#pragma unroll
    for (int r = 0; r < C; ++r) red[(q * C + r) * 128 + d] = acc[r];
  }
  __syncthreads();
  // layer-2 reduce: 8 partials + bias -> eout (LDS levels 2..8, global level 1)
  for (int idx = t; idx < 128 * C; idx += NTHR) {
    const int d2 = idx & 127, r2 = idx >> 7;
    float sum = B2[d2];
#pragma unroll
    for (int q2 = 0; q2 < 8; ++q2) sum += red[(q2 * C + r2) * 128 + d2];
    eout[r2 * 128 + d2] = sum;
  }
  __syncthreads();
}

// ---------------- one stage; KIN folded to 256 for both stage types --------
// ein: full input-row array (LDS for l>=2, global for l==1, root const l==0)
// stage_z: true for l==1 (stage global z rows through h_lds first)
__device__ void run_stage(const float* ein, int zstride, bool stage_z, int rows,
                          const int* u1h,
                          const float* __restrict__ W1, const float* __restrict__ B1,
                          const float* __restrict__ W2, const float* __restrict__ B2,
                          const float* __restrict__ lab,
                          float* __restrict__ h_lds, float* __restrict__ red_lds,
                          float* __restrict__ eout)
{
  const int t = threadIdx.x;
  int done = 0;
  while (done < rows) {
    int c = rows - done;
    if (c > CMAX) c = CMAX;
    const float* zb;
    int zs;
    if (stage_z) {
      const float* src = ein + done * 256;
      const int total = c * 256;
      for (int idx = 4 * t; idx < total; idx += 4 * NTHR)
        *reinterpret_cast<float4*>(h_lds + idx) =
            *reinterpret_cast<const float4*>(src + idx);
      __syncthreads();
      zb = h_lds; zs = 256;
    } else {
      zb = zstride ? ein + done * 256 : ein;
      zs = zstride;
    }
    float* eo = eout + done * 128;
    switch (c) {
      case 8:  mlp_chunk<8>(zb, zs, W1, B1, W2, B2, lab, u1h, done, h_lds, red_lds, eo); break;
      case 4:  mlp_chunk<4>(zb, zs, W1, B1, W2, B2, lab, u1h, done, h_lds, red_lds, eo); break;
      case 2:  mlp_chunk<2>(zb, zs, W1, B1, W2, B2, lab, u1h, done, h_lds, red_lds, eo); break;
      default: mlp_chunk<1>(zb, zs, W1, B1, W2, B2, lab, u1h, done, h_lds, red_lds, eo); break;
    }
    done += c;
  }
}

__global__ void sc_setup(const int* __restrict__ info_set,
                         const float* __restrict__ E_obs,
                         const float* __restrict__ E_lab,
                         const float* __restrict__ Wb1,
                         int* __restrict__ pos2k, float* __restrict__ lab1,
                         float* __restrict__ eroot)
{
  const int t = threadIdx.x;   // 256 threads
  pos2k[t] = -1;
  __syncthreads();
  if (t < 128) pos2k[info_set[t]] = t;
  eroot[t] = E_obs[2 * 128 + (t & 127)];
  // lab1[j][h] = sum_k E_lab[j,k] * Wb1[256+k, h]
  for (int j = 0; j < 2; ++j) {
    float s = 0.0f;
    for (int k = 0; k < 128; ++k)
      s = fmaf(E_lab[j * 128 + k], Wb1[(256 + k) * 256 + t], s);
    lab1[j * 256 + t] = s;
  }
}

__global__ __launch_bounds__(NTHR, 2)
void sc_main(const int* __restrict__ info_bits, const float* __restrict__ rin,
             const float* __restrict__ Wc1, const float* __restrict__ bc1,
             const float* __restrict__ Wc2, const float* __restrict__ bc2,
             const float* __restrict__ Wb1, const float* __restrict__ bb1,
             const float* __restrict__ Wb2, const float* __restrict__ bb2,
             const float* __restrict__ Wl, const float* __restrict__ bl,
             const int* __restrict__ pos2k, const float* __restrict__ lab1_g,
             const float* __restrict__ eroot_g,
             float* __restrict__ wsall, float* __restrict__ out)
{
  const int b = blockIdx.x;   // one block per batch element
  const int t = threadIdx.x;
  float* e1g = wsall + (size_t)b * L1_SIZE;   // level-1 e-buffer (global)

  __shared__ float e_lds[16256];          // e levels 2..8   (63.5 KB)
  __shared__ float h_lds[CMAX * 256];     //  8 KB (also z-staging for l==1)
  __shared__ float red_lds[8192];         // 32 KB
  __shared__ float lab_lds[512];          //  2 KB
  __shared__ float eroot[256];            //  1 KB
  __shared__ int   xh[512];               //  2 KB

  for (int idx = t; idx < 512; idx += NTHR) lab_lds[idx] = lab1_g[idx];
  if (t < 256) eroot[t] = eroot_g[t];
  __syncthreads();

  float* xO = out;
  float* fO = out + 32768;
  float* uO = out + 65536;
  float* pO = out + 98304;
  float* rO = out + 131072;

  // input pointer / stride / staging + output pointer per stage level
  auto zin = [&](int l) -> const float* {
    return (l == 0) ? eroot : (l == 1) ? e1g : e_lds + ldse(l);
  };
  auto zstr  = [&](int l) { return (l == 0) ? 0 : 256; };
  auto eoutp = [&](int l) -> float* {       // stage level l writes level l+1
    return (l == 0) ? e1g : e_lds + ldse(l + 1);
  };

  auto do_check = [&](int l) {
    run_stage(zin(l), zstr(l), l == 1, 128 >> l, nullptr,
              Wc1, bc1, Wc2, bc2, nullptr, h_lds, red_lds, eoutp(l));
  };
  auto do_bit = [&](int l) {
    run_stage(zin(l), zstr(l), l == 1, 128 >> l, xh + xoff(l),
              Wb1, bb1, Wb2, bb2, lab_lds, h_lds, red_lds, eoutp(l));
  };
  auto do_leaf = [&](int i) {
    const float* e = e_lds + ldse(8);  // 1 row, 128 floats
    if (t < 64) {
      float partial = e[t] * Wl[t] + e[t + 64] * Wl[t + 64];
#pragma unroll
      for (int m = 32; m >= 1; m >>= 1) partial += __shfl_xor(partial, m);
      if (t == 0) {
        const float tv = partial + bl[0];
        const float p  = 1.0f / (1.0f + expf(-tv));
        const float rv = rin[b * 256 + i];
        const int  hd     = (rv > p) ? 1 : 0;
        const bool frozen = fabsf(p - 0.5f) > 0.25f;
        const int  k  = pos2k[i];
        const int  fc = (k >= 0) ? info_bits[b * 128 + k] : 2;
        const int  x  = (fc == 2 || frozen) ? hd : fc;
        xh[xoff(7) + (i & 1)] = x;
        pO[b * 256 + i] = p;
        uO[b * 256 + i] = (float)x;
        fO[b * 256 + i] = (k >= 0) ? 2.0f : 1.0f;
        rO[b * 256 + i] = rv;
      }
    }
    __syncthreads();
  };
  auto do_combine = [&](int l, int side) {
    const int n = 256 >> l, half = n >> 1;
    if (t < half) {
      const int u1 = xh[xoff(l) + t];
      const int u2 = xh[xoff(l) + half + t];
      if (l > 0) {
        const int base = xoff(l - 1) + side * n;
        xh[base + 2 * t]     = u1 ^ u2;
        xh[base + 2 * t + 1] = u2;
      } else {
        xO[b * 256 + 2 * t]     = (float)(u1 ^ u2);
        xO[b * 256 + 2 * t + 1] = (float)u2;
      }
    }
    __syncthreads();
  };

  // initial descent to leaf 0
  for (int l = 0; l < 8; ++l) do_check(l);
  do_leaf(0);

  for (int i = 1; i < 256; ++i) {
    const int s = __builtin_ctz(i);
    // fold completed subtrees upward; last fold lands as u1h (side 0)
    for (int j = 1; j <= s; ++j) do_combine(8 - j, (j < s) ? 1 : 0);
    const int lb = 7 - s;
    do_bit(lb);
    for (int l = lb + 1; l < 8; ++l) do_check(l);
    do_leaf(i);
  }
  // final folds; level-0 combine writes the codeword x
  for (int j = 1; j <= 8; ++j) do_combine(8 - j, 1);
}

extern "C" void kernel_launch(void* const* d_in, const int* in_sizes, int n_in,
                              void* d_out, int out_size, void* d_ws, size_t ws_size,
                              hipStream_t stream)
{
  const int*   info_bits = (const int*)  d_in[0];
  const float* rin       = (const float*)d_in[1];
  const int*   info_set  = (const int*)  d_in[2];
  const float* E_obs     = (const float*)d_in[3];
  const float* E_lab     = (const float*)d_in[4];
  const float* Wc1 = (const float*)d_in[5];
  const float* bc1 = (const float*)d_in[6];
  const float* Wc2 = (const float*)d_in[7];
  const float* bc2 = (const float*)d_in[8];
  const float* Wb1 = (const float*)d_in[9];
  const float* bb1 = (const float*)d_in[10];
  const float* Wb2 = (const float*)d_in[11];
  const float* bb2 = (const float*)d_in[12];
  const float* Wl  = (const float*)d_in[13];
  const float* bl  = (const float*)d_in[14];

  int*   pos2k = (int*)d_ws;                 // 256 ints
  float* lab1  = (float*)d_ws + 256;         // 512 floats
  float* eroot = (float*)d_ws + 768;         // 256 floats
  float* wsall = (float*)d_ws + 1024;        // 128 x 16384 floats (level-1)

  hipLaunchKernelGGL(sc_setup, dim3(1), dim3(256), 0, stream,
                     info_set, E_obs, E_lab, Wb1, pos2k, lab1, eroot);
  hipLaunchKernelGGL(sc_main, dim3(128), dim3(NTHR), 0, stream,
                     info_bits, rin,
                     Wc1, bc1, Wc2, bc2, Wb1, bb1, Wb2, bb2, Wl, bl,
                     pos2k, lab1, eroot, wsall, (float*)d_out);
}